// Round 1
// baseline (322.848 us; speedup 1.0000x reference)
//
#include <hip/hip_runtime.h>
#include <stdint.h>

// Problem constants (fixed by setup_inputs)
#define NIMG 32768   // B*R
#define DD   1024
#define LL   128
#define BBATCH 128
#define RTOK 256

typedef __attribute__((ext_vector_type(4))) float  f32x4;
typedef __attribute__((ext_vector_type(8))) short  s16x8;
typedef __attribute__((ext_vector_type(4))) short  s16x4;

__device__ __forceinline__ unsigned short f2bf(float x) {
  union { float f; unsigned int u; } a; a.f = x;
  unsigned int lsb = (a.u >> 16) & 1u;
  a.u += 0x7fffu + lsb;                    // round-to-nearest-even
  return (unsigned short)(a.u >> 16);
}
__device__ __forceinline__ float bf2f(unsigned short h) {
  union { unsigned int u; float f; } a; a.u = ((unsigned int)h) << 16; return a.f;
}

// async global->LDS, 16B per lane. LDS dest is wave-uniform base + lane*16.
__device__ __forceinline__ void gload_lds16(const void* g, void* s) {
  __builtin_amdgcn_global_load_lds(
      (__attribute__((address_space(1))) void*)g,
      (__attribute__((address_space(3))) void*)s, 16, 0, 0);
}

// ---------------- K1: img f32 -> bf16 hi + lo residual ----------------
__global__ __launch_bounds__(256) void k_convert_img(
    const float* __restrict__ in, unsigned short* __restrict__ hi,
    unsigned short* __restrict__ lo, int n4) {
  int idx = blockIdx.x * 256 + threadIdx.x;
  int stride = gridDim.x * 256;
  for (int i = idx; i < n4; i += stride) {
    f32x4 v = ((const f32x4*)in)[i];
    s16x4 h, l;
#pragma unroll
    for (int j = 0; j < 4; j++) {
      unsigned short hb = f2bf(v[j]);
      h[j] = (short)hb;
      l[j] = (short)f2bf(v[j] - bf2f(hb));
    }
    ((s16x4*)hi)[i] = h;
    ((s16x4*)lo)[i] = l;
  }
}

// ---------------- K2: f32 -> bf16 (hi only) ----------------
__global__ __launch_bounds__(256) void k_convert_hi(
    const float* __restrict__ in, unsigned short* __restrict__ out, int n4) {
  int i = blockIdx.x * 256 + threadIdx.x;
  if (i < n4) {
    f32x4 v = ((const f32x4*)in)[i];
    s16x4 h;
#pragma unroll
    for (int j = 0; j < 4; j++) h[j] = (short)f2bf(v[j]);
    ((s16x4*)out)[i] = h;
  }
}

// ---------------- K3: f32 TN gemm: C[m][n] = sum_k A[m][k]*B[n][k] + bias[n] ----------------
__global__ __launch_bounds__(256) void k_gemm_f32_tn(
    const float* __restrict__ A, const float* __restrict__ Bm,
    const float* __restrict__ bias, float* __restrict__ C,
    int M, int N, int K) {
  __shared__ float As[32][33], Bs[32][33];
  int tid = threadIdx.x;
  int bm = blockIdx.x * 32, bn = blockIdx.y * 32;
  int tr = tid & 31, tq = tid >> 5;
  float acc[4] = {0.f, 0.f, 0.f, 0.f};
  for (int k0 = 0; k0 < K; k0 += 32) {
#pragma unroll
    for (int i = 0; i < 4; i++) {
      int idx = tid + i * 256;
      int r = idx >> 5, c = idx & 31;
      As[r][c] = A[(size_t)(bm + r) * K + k0 + c];
      Bs[r][c] = Bm[(size_t)(bn + r) * K + k0 + c];
    }
    __syncthreads();
#pragma unroll
    for (int kk = 0; kk < 32; kk++) {
      float b = Bs[tr][kk];
#pragma unroll
      for (int i = 0; i < 4; i++) acc[i] += As[tq * 4 + i][kk] * b;
    }
    __syncthreads();
  }
#pragma unroll
  for (int i = 0; i < 4; i++)
    C[(size_t)(bm + tq * 4 + i) * N + bn + tr] = acc[i] + bias[bn + tr];
}

// ---------------- K4: f32 NN gemm + bf16 hi/lo split output ----------------
// C[m][n] = sum_k A[m][k]*B[k][n]; write Chi/Clo (bf16 split)
__global__ __launch_bounds__(256) void k_gemm_f32_nn_split(
    const float* __restrict__ A, const float* __restrict__ Bm,
    unsigned short* __restrict__ Chi, unsigned short* __restrict__ Clo,
    int M, int N, int K) {
  __shared__ float As[32][33], Bs[32][33];
  int tid = threadIdx.x;
  int bm = blockIdx.x * 32, bn = blockIdx.y * 32;
  int tr = tid & 31, tq = tid >> 5;
  float acc[4] = {0.f, 0.f, 0.f, 0.f};
  for (int k0 = 0; k0 < K; k0 += 32) {
#pragma unroll
    for (int i = 0; i < 4; i++) {
      int idx = tid + i * 256;
      int r = idx >> 5, c = idx & 31;
      As[r][c] = A[(size_t)(bm + r) * K + k0 + c];
      Bs[r][c] = Bm[(size_t)(k0 + r) * N + bn + c];
    }
    __syncthreads();
#pragma unroll
    for (int kk = 0; kk < 32; kk++) {
      float b = Bs[kk][tr];
#pragma unroll
      for (int i = 0; i < 4; i++) acc[i] += As[tq * 4 + i][kk] * b;
    }
    __syncthreads();
  }
#pragma unroll
  for (int i = 0; i < 4; i++) {
    float q = acc[i];
    unsigned short hb = f2bf(q);
    size_t o = (size_t)(bm + tq * 4 + i) * N + bn + tr;
    Chi[o] = hb;
    Clo[o] = f2bf(q - bf2f(hb));
  }
}

// ---------------- K5: bf16 MFMA TN gemm -> Vt[b][d][r] (+bias over m) ----------------
// C[m][n] = sum_k Wv[m][k]*img[n][k] + bv[m]; store bf16 at Vt[n>>8][m][n&255]
__global__ __launch_bounds__(256, 2) void k_gemm_v(
    const unsigned short* __restrict__ A, const unsigned short* __restrict__ Bm,
    const float* __restrict__ bv, unsigned short* __restrict__ Vt) {
  __shared__ unsigned short As[4096], Bs[4096];
  int tid = threadIdx.x, l = tid & 63, w = tid >> 6;
  int wm = w >> 1, wn = w & 1;
  int bm = blockIdx.x * 128, bn = blockIdx.y * 128;
  int lr = l & 15, lk = (l >> 4) * 8;
  f32x4 acc[4][4] = {};
  for (int k0 = 0; k0 < 1024; k0 += 32) {
#pragma unroll
    for (int rnd = 0; rnd < 2; rnd++) {
      int e = (rnd * 256 + tid) * 8;
      int row = e >> 5, col = e & 31;
      int lbase = rnd * 2048 + w * 512;
      gload_lds16(A + (size_t)(bm + row) * 1024 + k0 + col, &As[lbase]);
      gload_lds16(Bm + (size_t)(bn + row) * 1024 + k0 + col, &Bs[lbase]);
    }
    __syncthreads();
    s16x8 af[4], bf[4];
#pragma unroll
    for (int i = 0; i < 4; i++) af[i] = *(const s16x8*)&As[(wm * 64 + i * 16 + lr) * 32 + lk];
#pragma unroll
    for (int i = 0; i < 4; i++) bf[i] = *(const s16x8*)&Bs[(wn * 64 + i * 16 + lr) * 32 + lk];
#pragma unroll
    for (int i = 0; i < 4; i++)
#pragma unroll
      for (int j = 0; j < 4; j++)
        acc[i][j] = __builtin_amdgcn_mfma_f32_16x16x32_bf16(af[i], bf[j], acc[i][j], 0, 0, 0);
    __syncthreads();
  }
  int rh = (l >> 4) * 4;
#pragma unroll
  for (int i = 0; i < 4; i++) {
#pragma unroll
    for (int q = 0; q < 4; q++) {
      int gm = bm + wm * 64 + i * 16 + rh + q;
      float bias = bv[gm];
#pragma unroll
      for (int j = 0; j < 4; j++) {
        int gn = bn + wn * 64 + j * 16 + lr;
        int bb = gn >> 8, rr = gn & 255;
        Vt[(size_t)bb * 262144 + (size_t)gm * 256 + rr] = f2bf(acc[i][j][q] + bias);
      }
    }
  }
}

// ---------------- K6: 3-pass split-bf16 TN gemm -> scores f32 [128][32768] ----------------
// scores[m][n] = sum_k QW[m][k]*img[n][k] with QW,img each split hi/lo.
__global__ __launch_bounds__(256, 2) void k_gemm_scores(
    const unsigned short* __restrict__ Ah, const unsigned short* __restrict__ Al,
    const unsigned short* __restrict__ Bh, const unsigned short* __restrict__ Bl,
    float* __restrict__ S) {
  __shared__ unsigned short Ahs[4096], Als[4096], Bhs[4096], Bls[4096];
  int tid = threadIdx.x, l = tid & 63, w = tid >> 6;
  int wm = w >> 1, wn = w & 1;
  int bn = blockIdx.x * 128;
  int lr = l & 15, lk = (l >> 4) * 8;
  f32x4 acc[4][4] = {};
  for (int k0 = 0; k0 < 1024; k0 += 32) {
#pragma unroll
    for (int rnd = 0; rnd < 2; rnd++) {
      int e = (rnd * 256 + tid) * 8;
      int row = e >> 5, col = e & 31;
      size_t ga = (size_t)row * 1024 + k0 + col;
      size_t gb = (size_t)(bn + row) * 1024 + k0 + col;
      int lbase = rnd * 2048 + w * 512;
      gload_lds16(Ah + ga, &Ahs[lbase]);
      gload_lds16(Al + ga, &Als[lbase]);
      gload_lds16(Bh + gb, &Bhs[lbase]);
      gload_lds16(Bl + gb, &Bls[lbase]);
    }
    __syncthreads();
    s16x8 ah[4], al[4], bh[4], bl[4];
#pragma unroll
    for (int i = 0; i < 4; i++) {
      int ro = (wm * 64 + i * 16 + lr) * 32 + lk;
      ah[i] = *(const s16x8*)&Ahs[ro];
      al[i] = *(const s16x8*)&Als[ro];
    }
#pragma unroll
    for (int i = 0; i < 4; i++) {
      int ro = (wn * 64 + i * 16 + lr) * 32 + lk;
      bh[i] = *(const s16x8*)&Bhs[ro];
      bl[i] = *(const s16x8*)&Bls[ro];
    }
#pragma unroll
    for (int i = 0; i < 4; i++)
#pragma unroll
      for (int j = 0; j < 4; j++) {
        acc[i][j] = __builtin_amdgcn_mfma_f32_16x16x32_bf16(ah[i], bh[j], acc[i][j], 0, 0, 0);
        acc[i][j] = __builtin_amdgcn_mfma_f32_16x16x32_bf16(ah[i], bl[j], acc[i][j], 0, 0, 0);
        acc[i][j] = __builtin_amdgcn_mfma_f32_16x16x32_bf16(al[i], bh[j], acc[i][j], 0, 0, 0);
      }
    __syncthreads();
  }
  int rh = (l >> 4) * 4;
#pragma unroll
  for (int i = 0; i < 4; i++)
#pragma unroll
    for (int q = 0; q < 4; q++) {
      int gm = wm * 64 + i * 16 + rh + q;
#pragma unroll
      for (int j = 0; j < 4; j++) {
        int gn = bn + wn * 64 + j * 16 + lr;
        S[(size_t)gm * 32768 + gn] = acc[i][j][q];
      }
    }
}

// ---------------- K7: softmax over r (256) + *1/32, f32 -> bf16 ----------------
__global__ __launch_bounds__(256) void k_softmax(
    const float* __restrict__ S, unsigned short* __restrict__ P) {
  int w = threadIdx.x >> 6, l = threadIdx.x & 63;
  int row = blockIdx.x * 4 + w;            // (l*128 + b), 16384 rows
  const float* src = S + (size_t)row * 256;
  f32x4 x = ((const f32x4*)src)[l];
  float m = fmaxf(fmaxf(x[0], x[1]), fmaxf(x[2], x[3]));
#pragma unroll
  for (int s = 1; s < 64; s <<= 1) m = fmaxf(m, __shfl_xor(m, s, 64));
  f32x4 e;
  float sum = 0.f;
#pragma unroll
  for (int j = 0; j < 4; j++) { e[j] = __expf(x[j] - m); sum += e[j]; }
#pragma unroll
  for (int s = 1; s < 64; s <<= 1) sum += __shfl_xor(sum, s, 64);
  float sc = 0.03125f / sum;
  s16x4 o;
#pragma unroll
  for (int j = 0; j < 4; j++) o[j] = (short)f2bf(e[j] * sc);
  ((s16x4*)(P + (size_t)row * 256))[l] = o;
}

// ---------------- K8: PV bf16 MFMA TN gemm -> out[b][l][d] f32 ----------------
// out[b][m][n] = sum_r atten[m][b*256+r] * Vt[b][n][r]
__global__ __launch_bounds__(256, 2) void k_gemm_pv(
    const unsigned short* __restrict__ P, const unsigned short* __restrict__ Vt,
    float* __restrict__ Out) {
  __shared__ unsigned short As[4096], Bs[4096];
  int tid = threadIdx.x, l = tid & 63, w = tid >> 6;
  int wm = w >> 1, wn = w & 1;
  int bn = blockIdx.x * 128;
  int b = blockIdx.y;
  const unsigned short* Bb = Vt + (size_t)b * 262144;
  int lr = l & 15, lk = (l >> 4) * 8;
  f32x4 acc[4][4] = {};
  for (int k0 = 0; k0 < 256; k0 += 32) {
#pragma unroll
    for (int rnd = 0; rnd < 2; rnd++) {
      int e = (rnd * 256 + tid) * 8;
      int row = e >> 5, col = e & 31;
      int lbase = rnd * 2048 + w * 512;
      gload_lds16(P + (size_t)row * 32768 + b * 256 + k0 + col, &As[lbase]);
      gload_lds16(Bb + (size_t)(bn + row) * 256 + k0 + col, &Bs[lbase]);
    }
    __syncthreads();
    s16x8 af[4], bf[4];
#pragma unroll
    for (int i = 0; i < 4; i++) af[i] = *(const s16x8*)&As[(wm * 64 + i * 16 + lr) * 32 + lk];
#pragma unroll
    for (int i = 0; i < 4; i++) bf[i] = *(const s16x8*)&Bs[(wn * 64 + i * 16 + lr) * 32 + lk];
#pragma unroll
    for (int i = 0; i < 4; i++)
#pragma unroll
      for (int j = 0; j < 4; j++)
        acc[i][j] = __builtin_amdgcn_mfma_f32_16x16x32_bf16(af[i], bf[j], acc[i][j], 0, 0, 0);
    __syncthreads();
  }
  int rh = (l >> 4) * 4;
#pragma unroll
  for (int i = 0; i < 4; i++)
#pragma unroll
    for (int q = 0; q < 4; q++) {
      int gm = wm * 64 + i * 16 + rh + q;
#pragma unroll
      for (int j = 0; j < 4; j++) {
        int gn = bn + wn * 64 + j * 16 + lr;
        Out[(size_t)b * 131072 + (size_t)gm * 1024 + gn] = acc[i][j][q];
      }
    }
}

extern "C" void kernel_launch(void* const* d_in, const int* in_sizes, int n_in,
                              void* d_out, int out_size, void* d_ws, size_t ws_size,
                              hipStream_t stream) {
  const float* cap = (const float*)d_in[0];
  const float* img = (const float*)d_in[1];
  const float* Wq  = (const float*)d_in[2];
  const float* bq  = (const float*)d_in[3];
  const float* Wk  = (const float*)d_in[4];
  // d_in[5] = bk: adds a per-(b,l) constant across r -> cancels in softmax. Unused.
  const float* Wv  = (const float*)d_in[6];
  const float* bv  = (const float*)d_in[7];
  float* out = (float*)d_out;

  // Workspace layout (total 162,529,280 B). img_lo region is reused for Vt
  // after the scores GEMM consumes img_lo (stream order guarantees safety).
  char* ws = (char*)d_ws;
  if (ws_size < 162529280ull) return;  // fail loudly (output stays poisoned)
  unsigned short* img_hi = (unsigned short*)(ws);
  unsigned short* img_lo = (unsigned short*)(ws + 67108864);
  float*          scores = (float*)(ws + 134217728);
  unsigned short* atten  = (unsigned short*)(ws + 150994944);
  float*          Qb     = (float*)(ws + 159383552);
  unsigned short* QWh    = (unsigned short*)(ws + 159907840);
  unsigned short* QWl    = (unsigned short*)(ws + 160169984);
  unsigned short* Wvh    = (unsigned short*)(ws + 160432128);
  unsigned short* Vt     = img_lo;  // alias: img_lo dead after k_gemm_scores

  k_convert_img<<<2048, 256, 0, stream>>>(img, img_hi, img_lo, 33554432 / 4);
  k_convert_hi<<<1024, 256, 0, stream>>>(Wv, Wvh, 1048576 / 4);
  // Q = cap @ Wq^T + bq  (f32)
  k_gemm_f32_tn<<<dim3(4, 32), 256, 0, stream>>>(cap, Wq, bq, Qb, 128, 1024, 1024);
  // QW = Q @ Wk  (f32 -> bf16 hi/lo)
  k_gemm_f32_nn_split<<<dim3(4, 32), 256, 0, stream>>>(Qb, Wk, QWh, QWl, 128, 1024, 1024);
  // scores = QW @ img^T  (3-pass split bf16, f32 out)
  k_gemm_scores<<<256, 256, 0, stream>>>(QWh, QWl, img_hi, img_lo, scores);
  // atten = softmax(scores) / 32  (bf16)
  k_softmax<<<4096, 256, 0, stream>>>(scores, atten);
  // Vt[b][d][r] = (img @ Wv^T + bv)^T per batch  (bf16)
  k_gemm_v<<<dim3(8, 256), 256, 0, stream>>>(Wvh, img_hi, bv, Vt);
  // out = atten @ V
  k_gemm_pv<<<dim3(8, 128), 256, 0, stream>>>(atten, Vt, out);
}

// Round 2
// 277.482 us; speedup vs baseline: 1.1635x; 1.1635x over previous
//
#include <hip/hip_runtime.h>
#include <stdint.h>

typedef __attribute__((ext_vector_type(4))) float  f32x4;
typedef __attribute__((ext_vector_type(8))) short  s16x8;
typedef __attribute__((ext_vector_type(4))) short  s16x4;

__device__ __forceinline__ unsigned short f2bf(float x) {
  union { float f; unsigned int u; } a; a.f = x;
  unsigned int lsb = (a.u >> 16) & 1u;
  a.u += 0x7fffu + lsb;                    // round-to-nearest-even
  return (unsigned short)(a.u >> 16);
}
__device__ __forceinline__ float bf2f(unsigned short h) {
  union { unsigned int u; float f; } a; a.u = ((unsigned int)h) << 16; return a.f;
}

// async global->LDS, 16B per lane. LDS dest must be wave-uniform base (+lane*16).
__device__ __forceinline__ void gload_lds16(const void* g, void* s) {
  __builtin_amdgcn_global_load_lds(
      (__attribute__((address_space(1))) void*)g,
      (__attribute__((address_space(3))) void*)s, 16, 0, 0);
}

// ---------------- K1: img f32 -> bf16 hi + lo residual ----------------
__global__ __launch_bounds__(256) void k_convert_img(
    const float* __restrict__ in, unsigned short* __restrict__ hi,
    unsigned short* __restrict__ lo, int n4) {
  int idx = blockIdx.x * 256 + threadIdx.x;
  int stride = gridDim.x * 256;
  for (int i = idx; i < n4; i += stride) {
    f32x4 v = ((const f32x4*)in)[i];
    s16x4 h, l;
#pragma unroll
    for (int j = 0; j < 4; j++) {
      unsigned short hb = f2bf(v[j]);
      h[j] = (short)hb;
      l[j] = (short)f2bf(v[j] - bf2f(hb));
    }
    ((s16x4*)hi)[i] = h;
    ((s16x4*)lo)[i] = l;
  }
}

// ---------------- K2: f32 -> bf16 (hi only) ----------------
__global__ __launch_bounds__(256) void k_convert_hi(
    const float* __restrict__ in, unsigned short* __restrict__ out, int n4) {
  int i = blockIdx.x * 256 + threadIdx.x;
  if (i < n4) {
    f32x4 v = ((const f32x4*)in)[i];
    s16x4 h;
#pragma unroll
    for (int j = 0; j < 4; j++) h[j] = (short)f2bf(v[j]);
    ((s16x4*)out)[i] = h;
  }
}

// ---------------- K3: f32 TN gemm: C[m][n] = sum_k A[m][k]*B[n][k] + bias[n] ----------------
__global__ __launch_bounds__(256) void k_gemm_f32_tn(
    const float* __restrict__ A, const float* __restrict__ Bm,
    const float* __restrict__ bias, float* __restrict__ C,
    int M, int N, int K) {
  __shared__ float As[32][33], Bs[32][33];
  int tid = threadIdx.x;
  int bm = blockIdx.x * 32, bn = blockIdx.y * 32;
  int tr = tid & 31, tq = tid >> 5;
  float acc[4] = {0.f, 0.f, 0.f, 0.f};
  for (int k0 = 0; k0 < K; k0 += 32) {
#pragma unroll
    for (int i = 0; i < 4; i++) {
      int idx = tid + i * 256;
      int r = idx >> 5, c = idx & 31;
      As[r][c] = A[(size_t)(bm + r) * K + k0 + c];
      Bs[r][c] = Bm[(size_t)(bn + r) * K + k0 + c];
    }
    __syncthreads();
#pragma unroll
    for (int kk = 0; kk < 32; kk++) {
      float b = Bs[tr][kk];
#pragma unroll
      for (int i = 0; i < 4; i++) acc[i] += As[tq * 4 + i][kk] * b;
    }
    __syncthreads();
  }
#pragma unroll
  for (int i = 0; i < 4; i++)
    C[(size_t)(bm + tq * 4 + i) * N + bn + tr] = acc[i] + bias[bn + tr];
}

// ---------------- K4: f32 NN gemm + bf16 hi/lo split output ----------------
__global__ __launch_bounds__(256) void k_gemm_f32_nn_split(
    const float* __restrict__ A, const float* __restrict__ Bm,
    unsigned short* __restrict__ Chi, unsigned short* __restrict__ Clo,
    int M, int N, int K) {
  __shared__ float As[32][33], Bs[32][33];
  int tid = threadIdx.x;
  int bm = blockIdx.x * 32, bn = blockIdx.y * 32;
  int tr = tid & 31, tq = tid >> 5;
  float acc[4] = {0.f, 0.f, 0.f, 0.f};
  for (int k0 = 0; k0 < K; k0 += 32) {
#pragma unroll
    for (int i = 0; i < 4; i++) {
      int idx = tid + i * 256;
      int r = idx >> 5, c = idx & 31;
      As[r][c] = A[(size_t)(bm + r) * K + k0 + c];
      Bs[r][c] = Bm[(size_t)(k0 + r) * N + bn + c];
    }
    __syncthreads();
#pragma unroll
    for (int kk = 0; kk < 32; kk++) {
      float b = Bs[kk][tr];
#pragma unroll
      for (int i = 0; i < 4; i++) acc[i] += As[tq * 4 + i][kk] * b;
    }
    __syncthreads();
  }
#pragma unroll
  for (int i = 0; i < 4; i++) {
    float q = acc[i];
    unsigned short hb = f2bf(q);
    size_t o = (size_t)(bm + tq * 4 + i) * N + bn + tr;
    Chi[o] = hb;
    Clo[o] = f2bf(q - bf2f(hb));
  }
}

// ---------------- K6: 3-pass split-bf16 TN gemm -> scores f32 [128][32768] ----------------
__global__ __launch_bounds__(256, 2) void k_gemm_scores(
    const unsigned short* __restrict__ Ah, const unsigned short* __restrict__ Al,
    const unsigned short* __restrict__ Bh, const unsigned short* __restrict__ Bl,
    float* __restrict__ S) {
  __shared__ unsigned short Ahs[4096], Als[4096], Bhs[4096], Bls[4096];
  int tid = threadIdx.x, l = tid & 63, w = tid >> 6;
  int wm = w >> 1, wn = w & 1;
  int bn = blockIdx.x * 128;
  int lr = l & 15, lk = (l >> 4) * 8;
  f32x4 acc[4][4] = {};
  for (int k0 = 0; k0 < 1024; k0 += 32) {
#pragma unroll
    for (int rnd = 0; rnd < 2; rnd++) {
      int e = (rnd * 256 + tid) * 8;
      int row = e >> 5, col = e & 31;
      size_t ga = (size_t)row * 1024 + k0 + col;
      size_t gb = (size_t)(bn + row) * 1024 + k0 + col;
      int lbase = rnd * 2048 + w * 512;
      gload_lds16(Ah + ga, &Ahs[lbase]);
      gload_lds16(Al + ga, &Als[lbase]);
      gload_lds16(Bh + gb, &Bhs[lbase]);
      gload_lds16(Bl + gb, &Bls[lbase]);
    }
    __syncthreads();
    s16x8 ah[4], al[4], bh[4], bl[4];
#pragma unroll
    for (int i = 0; i < 4; i++) {
      int ro = (wm * 64 + i * 16 + lr) * 32 + lk;
      ah[i] = *(const s16x8*)&Ahs[ro];
      al[i] = *(const s16x8*)&Als[ro];
    }
#pragma unroll
    for (int i = 0; i < 4; i++) {
      int ro = (wn * 64 + i * 16 + lr) * 32 + lk;
      bh[i] = *(const s16x8*)&Bhs[ro];
      bl[i] = *(const s16x8*)&Bls[ro];
    }
#pragma unroll
    for (int i = 0; i < 4; i++)
#pragma unroll
      for (int j = 0; j < 4; j++) {
        acc[i][j] = __builtin_amdgcn_mfma_f32_16x16x32_bf16(ah[i], bh[j], acc[i][j], 0, 0, 0);
        acc[i][j] = __builtin_amdgcn_mfma_f32_16x16x32_bf16(ah[i], bl[j], acc[i][j], 0, 0, 0);
        acc[i][j] = __builtin_amdgcn_mfma_f32_16x16x32_bf16(al[i], bh[j], acc[i][j], 0, 0, 0);
      }
    __syncthreads();
  }
  int rh = (l >> 4) * 4;
#pragma unroll
  for (int i = 0; i < 4; i++)
#pragma unroll
    for (int q = 0; q < 4; q++) {
      int gm = wm * 64 + i * 16 + rh + q;
#pragma unroll
      for (int j = 0; j < 4; j++) {
        int gn = bn + wn * 64 + j * 16 + lr;
        S[(size_t)gm * 32768 + gn] = acc[i][j][q];
      }
    }
}

// ---------------- K7: softmax over r (256) + *1/32, f32 -> bf16 [b][l][r] ----------------
__global__ __launch_bounds__(256) void k_softmax(
    const float* __restrict__ S, unsigned short* __restrict__ P) {
  int w = threadIdx.x >> 6, l = threadIdx.x & 63;
  int row = blockIdx.x * 4 + w;            // row = l*128 + b, 16384 rows
  const float* src = S + (size_t)row * 256;
  f32x4 x = ((const f32x4*)src)[l];
  float m = fmaxf(fmaxf(x[0], x[1]), fmaxf(x[2], x[3]));
#pragma unroll
  for (int s = 1; s < 64; s <<= 1) m = fmaxf(m, __shfl_xor(m, s, 64));
  f32x4 e;
  float sum = 0.f;
#pragma unroll
  for (int j = 0; j < 4; j++) { e[j] = __expf(x[j] - m); sum += e[j]; }
#pragma unroll
  for (int s = 1; s < 64; s <<= 1) sum += __shfl_xor(sum, s, 64);
  float sc = 0.03125f / sum;
  s16x4 o;
#pragma unroll
  for (int j = 0; j < 4; j++) o[j] = (short)f2bf(e[j] * sc);
  // transpose the (l,b) indexing: write to attenB[b][l][r]
  int bb = row & 127, ll = row >> 7;
  ((s16x4*)(P + ((size_t)bb * 128 + ll) * 256))[l] = o;
}

// ---------------- K9: ctx[b][l][d] = sum_r attenB[b][l][r] * img_hi[b][r][d] ----------------
// TN MFMA with B transposed into LDS via pack-pair reg staging + XOR swizzle.
__global__ __launch_bounds__(256, 2) void k_gemm_ctx(
    const unsigned short* __restrict__ P, const unsigned short* __restrict__ Bh,
    unsigned short* __restrict__ Cp) {
  __shared__ unsigned short As[4096];   // atten tile [128 l][32 r] linear
  __shared__ unsigned short Bs[4096];   // imgT tile  [128 d][32 r], 64B rows, XOR-swizzled
  int tid = threadIdx.x, l = tid & 63, w = tid >> 6;
  int wm = w >> 1, wn = w & 1;
  // XCD-aware decomposition: 1024 blocks; xcd = rid%8 owns 16 batches entirely.
  int rid = blockIdx.x;
  int xcd = rid & 7, lid = rid >> 3;
  int b = xcd * 16 + (lid >> 3);
  int d0 = (lid & 7) * 128;
  const unsigned short* Pb = P + (size_t)b * 32768;
  int lr = l & 15, lk = (l >> 4) * 8;
  int u = tid & 15, dc = tid >> 4;
  f32x4 acc[4][4] = {};
  for (int k0 = 0; k0 < 256; k0 += 32) {
    // A: atten rows, linear global_load_lds
#pragma unroll
    for (int rnd = 0; rnd < 2; rnd++) {
      int e = (rnd * 256 + tid) * 8;
      int row = e >> 5, col = e & 31;
      gload_lds16(Pb + (size_t)row * 256 + k0 + col, &As[rnd * 2048 + w * 512]);
    }
    // B: transpose-stage img_hi[b][k0+r][d0+d] -> Bs[d][r] (pairs of r in u32)
    {
      const unsigned short* gsrc =
          Bh + ((size_t)(b * 256 + k0 + 2 * u)) * 1024 + d0 + dc * 8;
      s16x8 g0 = *(const s16x8*)gsrc;
      s16x8 g1 = *(const s16x8*)(gsrc + 1024);
#pragma unroll
      for (int j = 0; j < 8; j++) {
        int d = dc * 8 + j;
        unsigned int w32 = (unsigned int)(unsigned short)g0[j] |
                           ((unsigned int)(unsigned short)g1[j] << 16);
        int byte = d * 64 + ((4 * u) ^ ((d & 3) << 4));
        *(unsigned int*)((char*)Bs + byte) = w32;
      }
    }
    __syncthreads();
    s16x8 af[4], bf[4];
#pragma unroll
    for (int i = 0; i < 4; i++)
      af[i] = *(const s16x8*)&As[(wm * 64 + i * 16 + lr) * 32 + lk];
#pragma unroll
    for (int j = 0; j < 4; j++) {
      int n = wn * 64 + j * 16 + lr;
      int byte = n * 64 + ((16 * (l >> 4)) ^ ((n & 3) << 4));
      bf[j] = *(const s16x8*)((const char*)Bs + byte);
    }
#pragma unroll
    for (int i = 0; i < 4; i++)
#pragma unroll
      for (int j = 0; j < 4; j++)
        acc[i][j] = __builtin_amdgcn_mfma_f32_16x16x32_bf16(af[i], bf[j], acc[i][j], 0, 0, 0);
    __syncthreads();
  }
  int rh = (l >> 4) * 4;
#pragma unroll
  for (int i = 0; i < 4; i++)
#pragma unroll
    for (int q = 0; q < 4; q++) {
      int gm = wm * 64 + i * 16 + rh + q;
#pragma unroll
      for (int j = 0; j < 4; j++) {
        int gn = wn * 64 + j * 16 + lr;
        Cp[((size_t)b * 128 + gm) * 1024 + d0 + gn] = f2bf(acc[i][j][q]);
      }
    }
}

// ---------------- K10: out[m][n] = sum_k ctx[m][k]*Wv[n][k] + bv[n]/32 ----------------
// M=16384, N=1024, K=1024. TN, m97-style, XCD-swizzled.
__global__ __launch_bounds__(256, 2) void k_gemm_out(
    const unsigned short* __restrict__ A, const unsigned short* __restrict__ Bm,
    const float* __restrict__ bv, float* __restrict__ Out) {
  __shared__ unsigned short As[4096], Bs[4096];
  int tid = threadIdx.x, l = tid & 63, w = tid >> 6;
  int wm = w >> 1, wn = w & 1;
  // 1024 blocks: xcd owns 16 consecutive M-tiles (all 8 N-tiles each) -> A panel L2-local
  int rid = blockIdx.x;
  int xcd = rid & 7, lid = rid >> 3;
  int bm = (xcd * 16 + (lid >> 3)) * 128;
  int bn = (lid & 7) * 128;
  int lr = l & 15, lk = (l >> 4) * 8;
  f32x4 acc[4][4] = {};
  for (int k0 = 0; k0 < 1024; k0 += 32) {
#pragma unroll
    for (int rnd = 0; rnd < 2; rnd++) {
      int e = (rnd * 256 + tid) * 8;
      int row = e >> 5, col = e & 31;
      int lbase = rnd * 2048 + w * 512;
      gload_lds16(A + (size_t)(bm + row) * 1024 + k0 + col, &As[lbase]);
      gload_lds16(Bm + (size_t)(bn + row) * 1024 + k0 + col, &Bs[lbase]);
    }
    __syncthreads();
    s16x8 af[4], bf[4];
#pragma unroll
    for (int i = 0; i < 4; i++) af[i] = *(const s16x8*)&As[(wm * 64 + i * 16 + lr) * 32 + lk];
#pragma unroll
    for (int i = 0; i < 4; i++) bf[i] = *(const s16x8*)&Bs[(wn * 64 + i * 16 + lr) * 32 + lk];
#pragma unroll
    for (int i = 0; i < 4; i++)
#pragma unroll
      for (int j = 0; j < 4; j++)
        acc[i][j] = __builtin_amdgcn_mfma_f32_16x16x32_bf16(af[i], bf[j], acc[i][j], 0, 0, 0);
    __syncthreads();
  }
  int rh = (l >> 4) * 4;
#pragma unroll
  for (int i = 0; i < 4; i++)
#pragma unroll
    for (int q = 0; q < 4; q++) {
      int gm = bm + wm * 64 + i * 16 + rh + q;
#pragma unroll
      for (int j = 0; j < 4; j++) {
        int gn = bn + wn * 64 + j * 16 + lr;
        Out[(size_t)gm * 1024 + gn] = acc[i][j][q] + 0.03125f * bv[gn];
      }
    }
}

extern "C" void kernel_launch(void* const* d_in, const int* in_sizes, int n_in,
                              void* d_out, int out_size, void* d_ws, size_t ws_size,
                              hipStream_t stream) {
  const float* cap = (const float*)d_in[0];
  const float* img = (const float*)d_in[1];
  const float* Wq  = (const float*)d_in[2];
  const float* bq  = (const float*)d_in[3];
  const float* Wk  = (const float*)d_in[4];
  // d_in[5] = bk: constant across r -> cancels in softmax. Unused.
  const float* Wv  = (const float*)d_in[6];
  const float* bv  = (const float*)d_in[7];
  float* out = (float*)d_out;

  char* ws = (char*)d_ws;
  if (ws_size < 162529280ull) return;  // fail loudly (output stays poisoned)
  unsigned short* img_hi = (unsigned short*)(ws);
  unsigned short* img_lo = (unsigned short*)(ws + 67108864);
  float*          scores = (float*)(ws + 134217728);
  unsigned short* atten  = (unsigned short*)(ws + 150994944);
  float*          Qb     = (float*)(ws + 159383552);
  unsigned short* QWh    = (unsigned short*)(ws + 159907840);
  unsigned short* QWl    = (unsigned short*)(ws + 160169984);
  unsigned short* Wvh    = (unsigned short*)(ws + 160432128);
  unsigned short* ctx    = img_lo;  // alias: img_lo dead after k_gemm_scores (32MB < 64MB)

  k_convert_img<<<2048, 256, 0, stream>>>(img, img_hi, img_lo, 33554432 / 4);
  k_convert_hi<<<1024, 256, 0, stream>>>(Wv, Wvh, 1048576 / 4);
  // Q = cap @ Wq^T + bq  (f32)
  k_gemm_f32_tn<<<dim3(4, 32), 256, 0, stream>>>(cap, Wq, bq, Qb, 128, 1024, 1024);
  // QW = Q @ Wk  (f32 -> bf16 hi/lo)
  k_gemm_f32_nn_split<<<dim3(4, 32), 256, 0, stream>>>(Qb, Wk, QWh, QWl, 128, 1024, 1024);
  // scores = QW @ img^T  (3-pass split bf16, f32 out)
  k_gemm_scores<<<256, 256, 0, stream>>>(QWh, QWl, img_hi, img_lo, scores);
  // atten[b][l][r] = softmax(scores) / 32  (bf16)
  k_softmax<<<4096, 256, 0, stream>>>(scores, atten);
  // ctx[b][l][d] = atten[b] @ img[b]  (bf16, transpose-staged B)
  k_gemm_ctx<<<1024, 256, 0, stream>>>(atten, img_hi, ctx);
  // out = ctx @ Wv^T + bv/32
  k_gemm_out<<<1024, 256, 0, stream>>>(ctx, Wvh, bv, out);
}

// Round 3
// 229.323 us; speedup vs baseline: 1.4078x; 1.2100x over previous
//
#include <hip/hip_runtime.h>
#include <stdint.h>

typedef __attribute__((ext_vector_type(4))) float  f32x4;
typedef __attribute__((ext_vector_type(8))) short  s16x8;
typedef __attribute__((ext_vector_type(4))) short  s16x4;

__device__ __forceinline__ unsigned short f2bf(float x) {
  union { float f; unsigned int u; } a; a.f = x;
  unsigned int lsb = (a.u >> 16) & 1u;
  a.u += 0x7fffu + lsb;                    // round-to-nearest-even
  return (unsigned short)(a.u >> 16);
}
__device__ __forceinline__ float bf2f(unsigned short h) {
  union { unsigned int u; float f; } a; a.u = ((unsigned int)h) << 16; return a.f;
}

// async global->LDS, 16B per lane. LDS dest must be wave-uniform base (+lane*16).
__device__ __forceinline__ void gload_lds16(const void* g, void* s) {
  __builtin_amdgcn_global_load_lds(
      (__attribute__((address_space(1))) void*)g,
      (__attribute__((address_space(3))) void*)s, 16, 0, 0);
}

// ---------------- K2: f32 -> bf16 (hi only) ----------------
__global__ __launch_bounds__(256) void k_convert_hi(
    const float* __restrict__ in, unsigned short* __restrict__ out, int n4) {
  int i = blockIdx.x * 256 + threadIdx.x;
  if (i < n4) {
    f32x4 v = ((const f32x4*)in)[i];
    s16x4 h;
#pragma unroll
    for (int j = 0; j < 4; j++) h[j] = (short)f2bf(v[j]);
    ((s16x4*)out)[i] = h;
  }
}

// ---------------- K3: f32 TN gemm: C[m][n] = sum_k A[m][k]*B[n][k] + bias[n] ----------------
__global__ __launch_bounds__(256) void k_gemm_f32_tn(
    const float* __restrict__ A, const float* __restrict__ Bm,
    const float* __restrict__ bias, float* __restrict__ C,
    int M, int N, int K) {
  __shared__ float As[32][33], Bs[32][33];
  int tid = threadIdx.x;
  int bm = blockIdx.x * 32, bn = blockIdx.y * 32;
  int tr = tid & 31, tq = tid >> 5;
  float acc[4] = {0.f, 0.f, 0.f, 0.f};
  for (int k0 = 0; k0 < K; k0 += 32) {
#pragma unroll
    for (int i = 0; i < 4; i++) {
      int idx = tid + i * 256;
      int r = idx >> 5, c = idx & 31;
      As[r][c] = A[(size_t)(bm + r) * K + k0 + c];
      Bs[r][c] = Bm[(size_t)(bn + r) * K + k0 + c];
    }
    __syncthreads();
#pragma unroll
    for (int kk = 0; kk < 32; kk++) {
      float b = Bs[tr][kk];
#pragma unroll
      for (int i = 0; i < 4; i++) acc[i] += As[tq * 4 + i][kk] * b;
    }
    __syncthreads();
  }
#pragma unroll
  for (int i = 0; i < 4; i++)
    C[(size_t)(bm + tq * 4 + i) * N + bn + tr] = acc[i] + bias[bn + tr];
}

// ---------------- K4: f32 NN gemm + bf16 hi/lo split output ----------------
__global__ __launch_bounds__(256) void k_gemm_f32_nn_split(
    const float* __restrict__ A, const float* __restrict__ Bm,
    unsigned short* __restrict__ Chi, unsigned short* __restrict__ Clo,
    int M, int N, int K) {
  __shared__ float As[32][33], Bs[32][33];
  int tid = threadIdx.x;
  int bm = blockIdx.x * 32, bn = blockIdx.y * 32;
  int tr = tid & 31, tq = tid >> 5;
  float acc[4] = {0.f, 0.f, 0.f, 0.f};
  for (int k0 = 0; k0 < K; k0 += 32) {
#pragma unroll
    for (int i = 0; i < 4; i++) {
      int idx = tid + i * 256;
      int r = idx >> 5, c = idx & 31;
      As[r][c] = A[(size_t)(bm + r) * K + k0 + c];
      Bs[r][c] = Bm[(size_t)(k0 + r) * N + bn + c];
    }
    __syncthreads();
#pragma unroll
    for (int kk = 0; kk < 32; kk++) {
      float b = Bs[kk][tr];
#pragma unroll
      for (int i = 0; i < 4; i++) acc[i] += As[tq * 4 + i][kk] * b;
    }
    __syncthreads();
  }
#pragma unroll
  for (int i = 0; i < 4; i++) {
    float q = acc[i];
    unsigned short hb = f2bf(q);
    size_t o = (size_t)(bm + tq * 4 + i) * N + bn + tr;
    Chi[o] = hb;
    Clo[o] = f2bf(q - bf2f(hb));
  }
}

// ---------------- K6: 3-pass split-bf16 TN gemm -> scores f32 [128][32768] ----------------
// A = QW (precomputed bf16 hi/lo). B = img f32, split hi/lo IN-REGISTER at staging.
// 512 threads = 8 waves (2 per SIMD) so split-VALU overlaps memory.
__global__ __launch_bounds__(512, 2) void k_gemm_scores(
    const unsigned short* __restrict__ Ah, const unsigned short* __restrict__ Al,
    const float* __restrict__ img, float* __restrict__ S) {
  __shared__ unsigned short Ahs[4096], Als[4096], Bhs[4096], Bls[4096];
  int tid = threadIdx.x, l = tid & 63, w = tid >> 6;
  int wm = w >> 2, wn = w & 3;              // 2 x 4 wave grid over 128x128 tile
  int bn = blockIdx.x * 128;
  int lr = l & 15, lk = (l >> 4) * 8;
  int brow = tid >> 2, bcol = (tid & 3) * 8; // B staging: 8 f32 per thread
  f32x4 acc[4][2] = {};
  for (int k0 = 0; k0 < 1024; k0 += 32) {
    // A tiles (8 KB each): one async round, wave-uniform LDS base
    {
      size_t ga = (size_t)(w * 64) * 8 + (size_t)(tid & 63) * 0;  // (see below)
      // lane-level source: element (w*64 + l)*8 spread as row=e>>5,col=e&31
      int e = tid * 8;
      int row = e >> 5, col = e & 31;
      size_t off = (size_t)row * 1024 + k0 + col;
      gload_lds16(Ah + off, &Ahs[w * 512]);
      gload_lds16(Al + off, &Als[w * 512]);
      (void)ga;
    }
    // B tile: reg-stage f32 -> hi/lo bf16, lane-contiguous ds_write (conflict-free)
    {
      const float* g = img + (size_t)(bn + brow) * 1024 + k0 + bcol;
      f32x4 v0 = *(const f32x4*)g;
      f32x4 v1 = *(const f32x4*)(g + 4);
      s16x8 h, lw;
#pragma unroll
      for (int j = 0; j < 4; j++) {
        unsigned short hb = f2bf(v0[j]);
        h[j] = (short)hb; lw[j] = (short)f2bf(v0[j] - bf2f(hb));
        unsigned short hb1 = f2bf(v1[j]);
        h[j + 4] = (short)hb1; lw[j + 4] = (short)f2bf(v1[j] - bf2f(hb1));
      }
      *(s16x8*)&Bhs[brow * 32 + bcol] = h;
      *(s16x8*)&Bls[brow * 32 + bcol] = lw;
    }
    __syncthreads();
    s16x8 ah[4], al4[4], bh[2], bl[2];
#pragma unroll
    for (int i = 0; i < 4; i++) {
      int ro = (wm * 64 + i * 16 + lr) * 32 + lk;
      ah[i] = *(const s16x8*)&Ahs[ro];
      al4[i] = *(const s16x8*)&Als[ro];
    }
#pragma unroll
    for (int j = 0; j < 2; j++) {
      int ro = (wn * 32 + j * 16 + lr) * 32 + lk;
      bh[j] = *(const s16x8*)&Bhs[ro];
      bl[j] = *(const s16x8*)&Bls[ro];
    }
#pragma unroll
    for (int i = 0; i < 4; i++)
#pragma unroll
      for (int j = 0; j < 2; j++) {
        acc[i][j] = __builtin_amdgcn_mfma_f32_16x16x32_bf16(ah[i], bh[j], acc[i][j], 0, 0, 0);
        acc[i][j] = __builtin_amdgcn_mfma_f32_16x16x32_bf16(ah[i], bl[j], acc[i][j], 0, 0, 0);
        acc[i][j] = __builtin_amdgcn_mfma_f32_16x16x32_bf16(al4[i], bh[j], acc[i][j], 0, 0, 0);
      }
    __syncthreads();
  }
  int rh = (l >> 4) * 4;
#pragma unroll
  for (int i = 0; i < 4; i++)
#pragma unroll
    for (int q = 0; q < 4; q++) {
      int gm = wm * 64 + i * 16 + rh + q;
#pragma unroll
      for (int j = 0; j < 2; j++) {
        int gn = bn + wn * 32 + j * 16 + lr;
        S[(size_t)gm * 32768 + gn] = acc[i][j][q];
      }
    }
}

// ---------------- K7: softmax over r (256) + *1/32, f32 -> bf16 [b][l][r] ----------------
__global__ __launch_bounds__(256) void k_softmax(
    const float* __restrict__ S, unsigned short* __restrict__ P) {
  int w = threadIdx.x >> 6, l = threadIdx.x & 63;
  int row = blockIdx.x * 4 + w;            // row = l*128 + b, 16384 rows
  const float* src = S + (size_t)row * 256;
  f32x4 x = ((const f32x4*)src)[l];
  float m = fmaxf(fmaxf(x[0], x[1]), fmaxf(x[2], x[3]));
#pragma unroll
  for (int s = 1; s < 64; s <<= 1) m = fmaxf(m, __shfl_xor(m, s, 64));
  f32x4 e;
  float sum = 0.f;
#pragma unroll
  for (int j = 0; j < 4; j++) { e[j] = __expf(x[j] - m); sum += e[j]; }
#pragma unroll
  for (int s = 1; s < 64; s <<= 1) sum += __shfl_xor(sum, s, 64);
  float sc = 0.03125f / sum;
  s16x4 o;
#pragma unroll
  for (int j = 0; j < 4; j++) o[j] = (short)f2bf(e[j] * sc);
  // transpose the (l,b) indexing: write to attenB[b][l][r]
  int bb = row & 127, ll = row >> 7;
  ((s16x4*)(P + ((size_t)bb * 128 + ll) * 256))[l] = o;
}

// ---------------- K9: ctx[b][l][d] = sum_r attenB[b][l][r] * img[b][r][d] ----------------
// TN MFMA; B read as f32, converted + transposed into LDS via pack-pair reg
// staging with XOR swizzle.
__global__ __launch_bounds__(256, 2) void k_gemm_ctx(
    const unsigned short* __restrict__ P, const float* __restrict__ img,
    unsigned short* __restrict__ Cp) {
  __shared__ unsigned short As[4096];   // atten tile [128 l][32 r] linear
  __shared__ unsigned short Bs[4096];   // imgT tile  [128 d][32 r], 64B rows, XOR-swizzled
  int tid = threadIdx.x, l = tid & 63, w = tid >> 6;
  int wm = w >> 1, wn = w & 1;
  // XCD-aware decomposition: 1024 blocks; xcd = rid%8 owns 16 batches entirely.
  int rid = blockIdx.x;
  int xcd = rid & 7, lid = rid >> 3;
  int b = xcd * 16 + (lid >> 3);
  int d0 = (lid & 7) * 128;
  const unsigned short* Pb = P + (size_t)b * 32768;
  int lr = l & 15, lk = (l >> 4) * 8;
  int u = tid & 15, dc = tid >> 4;
  f32x4 acc[4][4] = {};
  for (int k0 = 0; k0 < 256; k0 += 32) {
    // A: atten rows, linear global_load_lds
#pragma unroll
    for (int rnd = 0; rnd < 2; rnd++) {
      int e = (rnd * 256 + tid) * 8;
      int row = e >> 5, col = e & 31;
      gload_lds16(Pb + (size_t)row * 256 + k0 + col, &As[rnd * 2048 + w * 512]);
    }
    // B: transpose-stage img[b][k0+r][d0+d] f32 -> bf16 pairs -> Bs[d][r]
    {
      const float* gsrc = img + ((size_t)(b * 256 + k0 + 2 * u)) * 1024 + d0 + dc * 8;
      f32x4 a0 = *(const f32x4*)gsrc;
      f32x4 a1 = *(const f32x4*)(gsrc + 4);
      f32x4 b0 = *(const f32x4*)(gsrc + 1024);
      f32x4 b1 = *(const f32x4*)(gsrc + 1028);
#pragma unroll
      for (int j = 0; j < 8; j++) {
        float x0 = (j < 4) ? a0[j & 3] : a1[j & 3];
        float x1 = (j < 4) ? b0[j & 3] : b1[j & 3];
        int d = dc * 8 + j;
        unsigned int w32 = (unsigned int)f2bf(x0) | ((unsigned int)f2bf(x1) << 16);
        int byte = d * 64 + ((4 * u) ^ ((d & 3) << 4));
        *(unsigned int*)((char*)Bs + byte) = w32;
      }
    }
    __syncthreads();
    s16x8 af[4], bf[4];
#pragma unroll
    for (int i = 0; i < 4; i++)
      af[i] = *(const s16x8*)&As[(wm * 64 + i * 16 + lr) * 32 + lk];
#pragma unroll
    for (int j = 0; j < 4; j++) {
      int n = wn * 64 + j * 16 + lr;
      int byte = n * 64 + ((16 * (l >> 4)) ^ ((n & 3) << 4));
      bf[j] = *(const s16x8*)((const char*)Bs + byte);
    }
#pragma unroll
    for (int i = 0; i < 4; i++)
#pragma unroll
      for (int j = 0; j < 4; j++)
        acc[i][j] = __builtin_amdgcn_mfma_f32_16x16x32_bf16(af[i], bf[j], acc[i][j], 0, 0, 0);
    __syncthreads();
  }
  int rh = (l >> 4) * 4;
#pragma unroll
  for (int i = 0; i < 4; i++)
#pragma unroll
    for (int q = 0; q < 4; q++) {
      int gm = wm * 64 + i * 16 + rh + q;
#pragma unroll
      for (int j = 0; j < 4; j++) {
        int gn = wn * 64 + j * 16 + lr;
        Cp[((size_t)b * 128 + gm) * 1024 + d0 + gn] = f2bf(acc[i][j][q]);
      }
    }
}

// ---------------- K10: out[m][n] = sum_k ctx[m][k]*Wv[n][k] + bv[n]/32 ----------------
// M=16384, N=1024, K=1024. TN, m97-style, XCD-swizzled.
__global__ __launch_bounds__(256, 2) void k_gemm_out(
    const unsigned short* __restrict__ A, const unsigned short* __restrict__ Bm,
    const float* __restrict__ bv, float* __restrict__ Out) {
  __shared__ unsigned short As[4096], Bs[4096];
  int tid = threadIdx.x, l = tid & 63, w = tid >> 6;
  int wm = w >> 1, wn = w & 1;
  // 1024 blocks: xcd owns 16 consecutive M-tiles (all 8 N-tiles each) -> A panel L2-local
  int rid = blockIdx.x;
  int xcd = rid & 7, lid = rid >> 3;
  int bm = (xcd * 16 + (lid >> 3)) * 128;
  int bn = (lid & 7) * 128;
  int lr = l & 15, lk = (l >> 4) * 8;
  f32x4 acc[4][4] = {};
  for (int k0 = 0; k0 < 1024; k0 += 32) {
#pragma unroll
    for (int rnd = 0; rnd < 2; rnd++) {
      int e = (rnd * 256 + tid) * 8;
      int row = e >> 5, col = e & 31;
      int lbase = rnd * 2048 + w * 512;
      gload_lds16(A + (size_t)(bm + row) * 1024 + k0 + col, &As[lbase]);
      gload_lds16(Bm + (size_t)(bn + row) * 1024 + k0 + col, &Bs[lbase]);
    }
    __syncthreads();
    s16x8 af[4], bf[4];
#pragma unroll
    for (int i = 0; i < 4; i++) af[i] = *(const s16x8*)&As[(wm * 64 + i * 16 + lr) * 32 + lk];
#pragma unroll
    for (int i = 0; i < 4; i++) bf[i] = *(const s16x8*)&Bs[(wn * 64 + i * 16 + lr) * 32 + lk];
#pragma unroll
    for (int i = 0; i < 4; i++)
#pragma unroll
      for (int j = 0; j < 4; j++)
        acc[i][j] = __builtin_amdgcn_mfma_f32_16x16x32_bf16(af[i], bf[j], acc[i][j], 0, 0, 0);
    __syncthreads();
  }
  int rh = (l >> 4) * 4;
#pragma unroll
  for (int i = 0; i < 4; i++)
#pragma unroll
    for (int q = 0; q < 4; q++) {
      int gm = bm + wm * 64 + i * 16 + rh + q;
#pragma unroll
      for (int j = 0; j < 4; j++) {
        int gn = bn + wn * 64 + j * 16 + lr;
        Out[(size_t)gm * 1024 + gn] = acc[i][j][q] + 0.03125f * bv[gn];
      }
    }
}

extern "C" void kernel_launch(void* const* d_in, const int* in_sizes, int n_in,
                              void* d_out, int out_size, void* d_ws, size_t ws_size,
                              hipStream_t stream) {
  const float* cap = (const float*)d_in[0];
  const float* img = (const float*)d_in[1];
  const float* Wq  = (const float*)d_in[2];
  const float* bq  = (const float*)d_in[3];
  const float* Wk  = (const float*)d_in[4];
  // d_in[5] = bk: constant across r -> cancels in softmax. Unused.
  const float* Wv  = (const float*)d_in[6];
  const float* bv  = (const float*)d_in[7];
  float* out = (float*)d_out;

  char* ws = (char*)d_ws;
  if (ws_size < 61865984ull) return;  // fail loudly (output stays poisoned)
  float*          scores = (float*)(ws);                    // 16 MB
  unsigned short* atten  = (unsigned short*)(ws + 16777216); //  8 MB
  unsigned short* ctx    = (unsigned short*)(ws + 25165824); // 32 MB
  float*          Qb     = (float*)(ws + 58720256);          // 512 KB
  unsigned short* QWh    = (unsigned short*)(ws + 59244544); // 256 KB
  unsigned short* QWl    = (unsigned short*)(ws + 59506688); // 256 KB
  unsigned short* Wvh    = (unsigned short*)(ws + 59768832); //   2 MB

  k_convert_hi<<<1024, 256, 0, stream>>>(Wv, Wvh, 1048576 / 4);
  // Q = cap @ Wq^T + bq  (f32)
  k_gemm_f32_tn<<<dim3(4, 32), 256, 0, stream>>>(cap, Wq, bq, Qb, 128, 1024, 1024);
  // QW = Q @ Wk  (f32 -> bf16 hi/lo)
  k_gemm_f32_nn_split<<<dim3(4, 32), 256, 0, stream>>>(Qb, Wk, QWh, QWl, 128, 1024, 1024);
  // scores = QW @ img^T  (3-pass split bf16, img split in-register, f32 out)
  k_gemm_scores<<<256, 512, 0, stream>>>(QWh, QWl, img, scores);
  // atten[b][l][r] = softmax(scores) / 32  (bf16)
  k_softmax<<<4096, 256, 0, stream>>>(scores, atten);
  // ctx[b][l][d] = atten[b] @ img[b]  (bf16, f32-read transpose-staged B)
  k_gemm_ctx<<<1024, 256, 0, stream>>>(atten, img, ctx);
  // out = ctx @ Wv^T + bv/32
  k_gemm_out<<<1024, 256, 0, stream>>>(ctx, Wvh, bv, out);
}

// Round 4
// 228.194 us; speedup vs baseline: 1.4148x; 1.0049x over previous
//
#include <hip/hip_runtime.h>
#include <stdint.h>

typedef __attribute__((ext_vector_type(4))) float  f32x4;
typedef __attribute__((ext_vector_type(8))) short  s16x8;
typedef __attribute__((ext_vector_type(4))) short  s16x4;

__device__ __forceinline__ unsigned short f2bf(float x) {
  union { float f; unsigned int u; } a; a.f = x;
  unsigned int lsb = (a.u >> 16) & 1u;
  a.u += 0x7fffu + lsb;                    // round-to-nearest-even
  return (unsigned short)(a.u >> 16);
}
__device__ __forceinline__ float bf2f(unsigned short h) {
  union { unsigned int u; float f; } a; a.u = ((unsigned int)h) << 16; return a.f;
}

// async global->LDS, 16B per lane. LDS dest must be wave-uniform base (+lane*16).
__device__ __forceinline__ void gload_lds16(const void* g, void* s) {
  __builtin_amdgcn_global_load_lds(
      (__attribute__((address_space(1))) void*)g,
      (__attribute__((address_space(3))) void*)s, 16, 0, 0);
}

// ---------------- K2: f32 -> bf16 (hi only) ----------------
__global__ __launch_bounds__(256) void k_convert_hi(
    const float* __restrict__ in, unsigned short* __restrict__ out, int n4) {
  int i = blockIdx.x * 256 + threadIdx.x;
  if (i < n4) {
    f32x4 v = ((const f32x4*)in)[i];
    s16x4 h;
#pragma unroll
    for (int j = 0; j < 4; j++) h[j] = (short)f2bf(v[j]);
    ((s16x4*)out)[i] = h;
  }
}

// ---------------- K3: f32 TN gemm: C[m][n] = sum_k A[m][k]*B[n][k] + bias[n] ----------------
__global__ __launch_bounds__(256) void k_gemm_f32_tn(
    const float* __restrict__ A, const float* __restrict__ Bm,
    const float* __restrict__ bias, float* __restrict__ C,
    int M, int N, int K) {
  __shared__ float As[32][33], Bs[32][33];
  int tid = threadIdx.x;
  int bm = blockIdx.x * 32, bn = blockIdx.y * 32;
  int tr = tid & 31, tq = tid >> 5;
  float acc[4] = {0.f, 0.f, 0.f, 0.f};
  for (int k0 = 0; k0 < K; k0 += 32) {
#pragma unroll
    for (int i = 0; i < 4; i++) {
      int idx = tid + i * 256;
      int r = idx >> 5, c = idx & 31;
      As[r][c] = A[(size_t)(bm + r) * K + k0 + c];
      Bs[r][c] = Bm[(size_t)(bn + r) * K + k0 + c];
    }
    __syncthreads();
#pragma unroll
    for (int kk = 0; kk < 32; kk++) {
      float b = Bs[tr][kk];
#pragma unroll
      for (int i = 0; i < 4; i++) acc[i] += As[tq * 4 + i][kk] * b;
    }
    __syncthreads();
  }
#pragma unroll
  for (int i = 0; i < 4; i++)
    C[(size_t)(bm + tq * 4 + i) * N + bn + tr] = acc[i] + bias[bn + tr];
}

// ---------------- K4: f32 NN gemm + bf16 hi/lo split output ----------------
__global__ __launch_bounds__(256) void k_gemm_f32_nn_split(
    const float* __restrict__ A, const float* __restrict__ Bm,
    unsigned short* __restrict__ Chi, unsigned short* __restrict__ Clo,
    int M, int N, int K) {
  __shared__ float As[32][33], Bs[32][33];
  int tid = threadIdx.x;
  int bm = blockIdx.x * 32, bn = blockIdx.y * 32;
  int tr = tid & 31, tq = tid >> 5;
  float acc[4] = {0.f, 0.f, 0.f, 0.f};
  for (int k0 = 0; k0 < K; k0 += 32) {
#pragma unroll
    for (int i = 0; i < 4; i++) {
      int idx = tid + i * 256;
      int r = idx >> 5, c = idx & 31;
      As[r][c] = A[(size_t)(bm + r) * K + k0 + c];
      Bs[r][c] = Bm[(size_t)(k0 + r) * N + bn + c];
    }
    __syncthreads();
#pragma unroll
    for (int kk = 0; kk < 32; kk++) {
      float b = Bs[kk][tr];
#pragma unroll
      for (int i = 0; i < 4; i++) acc[i] += As[tq * 4 + i][kk] * b;
    }
    __syncthreads();
  }
#pragma unroll
  for (int i = 0; i < 4; i++) {
    float q = acc[i];
    unsigned short hb = f2bf(q);
    size_t o = (size_t)(bm + tq * 4 + i) * N + bn + tr;
    Chi[o] = hb;
    Clo[o] = f2bf(q - bf2f(hb));
  }
}

// ---------------- K6: 3-pass split-bf16 TN gemm -> score partials ----------------
// A = QW (bf16 hi/lo, 128 x 1024). B = img f32, split hi/lo in-register.
// Grid: 1024 blocks = 512 N-tiles (64 wide) x 2 K-halves. Each block sums its
// K-half into Sp[ks][128][32768] f32. 256 threads, 24 KB LDS -> 4 blocks/CU.
__global__ __launch_bounds__(256, 4) void k_gemm_scores(
    const unsigned short* __restrict__ Ah, const unsigned short* __restrict__ Al,
    const float* __restrict__ img, float* __restrict__ Sp) {
  __shared__ unsigned short Ahs[4096], Als[4096];   // [128][32]
  __shared__ unsigned short Bhs[2048], Bls[2048];   // [64][32]
  int tid = threadIdx.x, l = tid & 63, w = tid >> 6;
  int wm = w >> 1, wn = w & 1;              // 2 x 2 wave grid over 128x64 tile
  // XCD-bijective: xcd owns a contiguous 64-N-tile range, both K-halves.
  int bid = blockIdx.x;
  int xcd = bid & 7, local = bid >> 3;      // local 0..127
  int ks = local & 1;
  int bn = (xcd * 64 + (local >> 1)) * 64;
  int kbase = ks * 512;
  float* S = Sp + (size_t)ks * 4194304;
  int lr = l & 15, lk = (l >> 4) * 8;
  int brow = tid >> 2, bcol = (tid & 3) * 8;  // B staging: 8 f32 per thread, 64 rows
  f32x4 acc[4][2] = {};
  for (int kk0 = 0; kk0 < 512; kk0 += 32) {
    int k0 = kbase + kk0;
    // A tiles (8 KB each): two async rounds, wave-uniform LDS base
#pragma unroll
    for (int rnd = 0; rnd < 2; rnd++) {
      int e = (rnd * 256 + tid) * 8;
      int row = e >> 5, col = e & 31;
      size_t off = (size_t)row * 1024 + k0 + col;
      gload_lds16(Ah + off, &Ahs[rnd * 2048 + w * 512]);
      gload_lds16(Al + off, &Als[rnd * 2048 + w * 512]);
    }
    // B tile: reg-stage f32 -> hi/lo bf16, lane-contiguous ds_write (conflict-free)
    {
      const float* g = img + (size_t)(bn + brow) * 1024 + k0 + bcol;
      f32x4 v0 = *(const f32x4*)g;
      f32x4 v1 = *(const f32x4*)(g + 4);
      s16x8 h, lw;
#pragma unroll
      for (int j = 0; j < 4; j++) {
        unsigned short hb = f2bf(v0[j]);
        h[j] = (short)hb; lw[j] = (short)f2bf(v0[j] - bf2f(hb));
        unsigned short hb1 = f2bf(v1[j]);
        h[j + 4] = (short)hb1; lw[j + 4] = (short)f2bf(v1[j] - bf2f(hb1));
      }
      *(s16x8*)&Bhs[brow * 32 + bcol] = h;
      *(s16x8*)&Bls[brow * 32 + bcol] = lw;
    }
    __syncthreads();
    s16x8 ah[4], al4[4], bh[2], bl[2];
#pragma unroll
    for (int i = 0; i < 4; i++) {
      int ro = (wm * 64 + i * 16 + lr) * 32 + lk;
      ah[i] = *(const s16x8*)&Ahs[ro];
      al4[i] = *(const s16x8*)&Als[ro];
    }
#pragma unroll
    for (int j = 0; j < 2; j++) {
      int ro = (wn * 32 + j * 16 + lr) * 32 + lk;
      bh[j] = *(const s16x8*)&Bhs[ro];
      bl[j] = *(const s16x8*)&Bls[ro];
    }
#pragma unroll
    for (int i = 0; i < 4; i++)
#pragma unroll
      for (int j = 0; j < 2; j++) {
        acc[i][j] = __builtin_amdgcn_mfma_f32_16x16x32_bf16(ah[i], bh[j], acc[i][j], 0, 0, 0);
        acc[i][j] = __builtin_amdgcn_mfma_f32_16x16x32_bf16(ah[i], bl[j], acc[i][j], 0, 0, 0);
        acc[i][j] = __builtin_amdgcn_mfma_f32_16x16x32_bf16(al4[i], bh[j], acc[i][j], 0, 0, 0);
      }
    __syncthreads();
  }
  int rh = (l >> 4) * 4;
#pragma unroll
  for (int i = 0; i < 4; i++)
#pragma unroll
    for (int q = 0; q < 4; q++) {
      int gm = wm * 64 + i * 16 + rh + q;
#pragma unroll
      for (int j = 0; j < 2; j++) {
        int gn = bn + wn * 32 + j * 16 + lr;
        S[(size_t)gm * 32768 + gn] = acc[i][j][q];
      }
    }
}

// ---------------- K7: softmax over r (256): sum K-partials, *1/32, f32 -> bf16 [b][l][r] ----------------
__global__ __launch_bounds__(256) void k_softmax(
    const float* __restrict__ S0, unsigned short* __restrict__ P) {
  const float* S1 = S0 + 4194304;
  int w = threadIdx.x >> 6, l = threadIdx.x & 63;
  int row = blockIdx.x * 4 + w;            // row = l*128 + b, 16384 rows
  f32x4 x0 = ((const f32x4*)(S0 + (size_t)row * 256))[l];
  f32x4 x1 = ((const f32x4*)(S1 + (size_t)row * 256))[l];
  f32x4 x;
#pragma unroll
  for (int j = 0; j < 4; j++) x[j] = x0[j] + x1[j];
  float m = fmaxf(fmaxf(x[0], x[1]), fmaxf(x[2], x[3]));
#pragma unroll
  for (int s = 1; s < 64; s <<= 1) m = fmaxf(m, __shfl_xor(m, s, 64));
  f32x4 e;
  float sum = 0.f;
#pragma unroll
  for (int j = 0; j < 4; j++) { e[j] = __expf(x[j] - m); sum += e[j]; }
#pragma unroll
  for (int s = 1; s < 64; s <<= 1) sum += __shfl_xor(sum, s, 64);
  float sc = 0.03125f / sum;
  s16x4 o;
#pragma unroll
  for (int j = 0; j < 4; j++) o[j] = (short)f2bf(e[j] * sc);
  // transpose the (l,b) indexing: write to attenB[b][l][r]
  int bb = row & 127, ll = row >> 7;
  ((s16x4*)(P + ((size_t)bb * 128 + ll) * 256))[l] = o;
}

// ---------------- K9: ctx[b][l][d] = sum_r attenB[b][l][r] * img[b][r][d] ----------------
// TN MFMA; B read as f32, converted + transposed into LDS via pack-pair reg
// staging with XOR swizzle.
__global__ __launch_bounds__(256, 2) void k_gemm_ctx(
    const unsigned short* __restrict__ P, const float* __restrict__ img,
    unsigned short* __restrict__ Cp) {
  __shared__ unsigned short As[4096];   // atten tile [128 l][32 r] linear
  __shared__ unsigned short Bs[4096];   // imgT tile  [128 d][32 r], 64B rows, XOR-swizzled
  int tid = threadIdx.x, l = tid & 63, w = tid >> 6;
  int wm = w >> 1, wn = w & 1;
  // XCD-aware decomposition: 1024 blocks; xcd = rid%8 owns 16 batches entirely.
  int rid = blockIdx.x;
  int xcd = rid & 7, lid = rid >> 3;
  int b = xcd * 16 + (lid >> 3);
  int d0 = (lid & 7) * 128;
  const unsigned short* Pb = P + (size_t)b * 32768;
  int lr = l & 15, lk = (l >> 4) * 8;
  int u = tid & 15, dc = tid >> 4;
  f32x4 acc[4][4] = {};
  for (int k0 = 0; k0 < 256; k0 += 32) {
    // A: atten rows, linear global_load_lds
#pragma unroll
    for (int rnd = 0; rnd < 2; rnd++) {
      int e = (rnd * 256 + tid) * 8;
      int row = e >> 5, col = e & 31;
      gload_lds16(Pb + (size_t)row * 256 + k0 + col, &As[rnd * 2048 + w * 512]);
    }
    // B: transpose-stage img[b][k0+r][d0+d] f32 -> bf16 pairs -> Bs[d][r]
    {
      const float* gsrc = img + ((size_t)(b * 256 + k0 + 2 * u)) * 1024 + d0 + dc * 8;
      f32x4 a0 = *(const f32x4*)gsrc;
      f32x4 a1 = *(const f32x4*)(gsrc + 4);
      f32x4 b0 = *(const f32x4*)(gsrc + 1024);
      f32x4 b1 = *(const f32x4*)(gsrc + 1028);
#pragma unroll
      for (int j = 0; j < 8; j++) {
        float x0 = (j < 4) ? a0[j & 3] : a1[j & 3];
        float x1 = (j < 4) ? b0[j & 3] : b1[j & 3];
        int d = dc * 8 + j;
        unsigned int w32 = (unsigned int)f2bf(x0) | ((unsigned int)f2bf(x1) << 16);
        int byte = d * 64 + ((4 * u) ^ ((d & 3) << 4));
        *(unsigned int*)((char*)Bs + byte) = w32;
      }
    }
    __syncthreads();
    s16x8 af[4], bf[4];
#pragma unroll
    for (int i = 0; i < 4; i++)
      af[i] = *(const s16x8*)&As[(wm * 64 + i * 16 + lr) * 32 + lk];
#pragma unroll
    for (int j = 0; j < 4; j++) {
      int n = wn * 64 + j * 16 + lr;
      int byte = n * 64 + ((16 * (l >> 4)) ^ ((n & 3) << 4));
      bf[j] = *(const s16x8*)((const char*)Bs + byte);
    }
#pragma unroll
    for (int i = 0; i < 4; i++)
#pragma unroll
      for (int j = 0; j < 4; j++)
        acc[i][j] = __builtin_amdgcn_mfma_f32_16x16x32_bf16(af[i], bf[j], acc[i][j], 0, 0, 0);
    __syncthreads();
  }
  int rh = (l >> 4) * 4;
#pragma unroll
  for (int i = 0; i < 4; i++)
#pragma unroll
    for (int q = 0; q < 4; q++) {
      int gm = wm * 64 + i * 16 + rh + q;
#pragma unroll
      for (int j = 0; j < 4; j++) {
        int gn = wn * 64 + j * 16 + lr;
        Cp[((size_t)b * 128 + gm) * 1024 + d0 + gn] = f2bf(acc[i][j][q]);
      }
    }
}

// ---------------- K10: out[m][n] = sum_k ctx[m][k]*Wv[n][k] + bv[n]/32 ----------------
// M=16384, N=1024, K=1024. TN, m97-style, XCD-swizzled.
__global__ __launch_bounds__(256, 2) void k_gemm_out(
    const unsigned short* __restrict__ A, const unsigned short* __restrict__ Bm,
    const float* __restrict__ bv, float* __restrict__ Out) {
  __shared__ unsigned short As[4096], Bs[4096];
  int tid = threadIdx.x, l = tid & 63, w = tid >> 6;
  int wm = w >> 1, wn = w & 1;
  // 1024 blocks: xcd owns 16 consecutive M-tiles (all 8 N-tiles each) -> A panel L2-local
  int rid = blockIdx.x;
  int xcd = rid & 7, lid = rid >> 3;
  int bm = (xcd * 16 + (lid >> 3)) * 128;
  int bn = (lid & 7) * 128;
  int lr = l & 15, lk = (l >> 4) * 8;
  f32x4 acc[4][4] = {};
  for (int k0 = 0; k0 < 1024; k0 += 32) {
#pragma unroll
    for (int rnd = 0; rnd < 2; rnd++) {
      int e = (rnd * 256 + tid) * 8;
      int row = e >> 5, col = e & 31;
      int lbase = rnd * 2048 + w * 512;
      gload_lds16(A + (size_t)(bm + row) * 1024 + k0 + col, &As[lbase]);
      gload_lds16(Bm + (size_t)(bn + row) * 1024 + k0 + col, &Bs[lbase]);
    }
    __syncthreads();
    s16x8 af[4], bf[4];
#pragma unroll
    for (int i = 0; i < 4; i++) af[i] = *(const s16x8*)&As[(wm * 64 + i * 16 + lr) * 32 + lk];
#pragma unroll
    for (int i = 0; i < 4; i++) bf[i] = *(const s16x8*)&Bs[(wn * 64 + i * 16 + lr) * 32 + lk];
#pragma unroll
    for (int i = 0; i < 4; i++)
#pragma unroll
      for (int j = 0; j < 4; j++)
        acc[i][j] = __builtin_amdgcn_mfma_f32_16x16x32_bf16(af[i], bf[j], acc[i][j], 0, 0, 0);
    __syncthreads();
  }
  int rh = (l >> 4) * 4;
#pragma unroll
  for (int i = 0; i < 4; i++)
#pragma unroll
    for (int q = 0; q < 4; q++) {
      int gm = bm + wm * 64 + i * 16 + rh + q;
#pragma unroll
      for (int j = 0; j < 4; j++) {
        int gn = bn + wn * 64 + j * 16 + lr;
        Out[(size_t)gm * 1024 + gn] = acc[i][j][q] + 0.03125f * bv[gn];
      }
    }
}

extern "C" void kernel_launch(void* const* d_in, const int* in_sizes, int n_in,
                              void* d_out, int out_size, void* d_ws, size_t ws_size,
                              hipStream_t stream) {
  const float* cap = (const float*)d_in[0];
  const float* img = (const float*)d_in[1];
  const float* Wq  = (const float*)d_in[2];
  const float* bq  = (const float*)d_in[3];
  const float* Wk  = (const float*)d_in[4];
  // d_in[5] = bk: constant across r -> cancels in softmax. Unused.
  const float* Wv  = (const float*)d_in[6];
  const float* bv  = (const float*)d_in[7];
  float* out = (float*)d_out;

  char* ws = (char*)d_ws;
  if (ws_size < 78643200ull) return;  // fail loudly (output stays poisoned)
  float*          scores = (float*)(ws);                     // 32 MB (2 K-halves)
  unsigned short* atten  = (unsigned short*)(ws + 33554432); //  8 MB
  unsigned short* ctx    = (unsigned short*)(ws + 41943040); // 32 MB
  float*          Qb     = (float*)(ws + 75497472);          // 512 KB
  unsigned short* QWh    = (unsigned short*)(ws + 76021760); // 256 KB
  unsigned short* QWl    = (unsigned short*)(ws + 76283904); // 256 KB
  unsigned short* Wvh    = (unsigned short*)(ws + 76546048); //   2 MB

  k_convert_hi<<<1024, 256, 0, stream>>>(Wv, Wvh, 1048576 / 4);
  // Q = cap @ Wq^T + bq  (f32)
  k_gemm_f32_tn<<<dim3(4, 32), 256, 0, stream>>>(cap, Wq, bq, Qb, 128, 1024, 1024);
  // QW = Q @ Wk  (f32 -> bf16 hi/lo)
  k_gemm_f32_nn_split<<<dim3(4, 32), 256, 0, stream>>>(Qb, Wk, QWh, QWl, 128, 1024, 1024);
  // score partials = QW @ img^T  (3-pass split bf16, img split in-register)
  k_gemm_scores<<<1024, 256, 0, stream>>>(QWh, QWl, img, scores);
  // atten[b][l][r] = softmax(sum of partials) / 32  (bf16)
  k_softmax<<<4096, 256, 0, stream>>>(scores, atten);
  // ctx[b][l][d] = atten[b] @ img[b]  (bf16, f32-read transpose-staged B)
  k_gemm_ctx<<<1024, 256, 0, stream>>>(atten, img, ctx);
  // out = ctx @ Wv^T + bv/32
  k_gemm_out<<<1024, 256, 0, stream>>>(ctx, Wvh, bv, out);
}